// Round 13
// baseline (243.971 us; speedup 1.0000x reference)
//
#include <hip/hip_runtime.h>

// B=8, L=2048, C=256, D=32. Four attentions (ecg/pcg intra/inter),
// out = concat(inter + scalar*intra) -> (8,2048,512) f32.
//
// Pipeline (NO memset: every output element is plain-stored exactly once):
//   1) deint_kernel : x f32 interleaved -> xe, xp bf16 [16384][256]
//   2) proj_kernel  : r9-validated 20-job version. xe/xp @ w -> bf16 Q[4]
//      (pre-scaled log2e/sqrt(32)), K[4], V in GLOBAL FRAGMENT-SLOT ORDER
//      Vf[bb][kt64][slot]: slot(nt,kc2,v5)=(nt*8+kc2)*32+v5, 16B slots,
//      tile = 32KB. Gated V jobs exit when scalar == 0.
//   3) flash_half : FAST PATH (scalar==0). NTN=2 + vh-split for TLP: 2048
//      blocks x 256 thr; block = 64q x 64vc; wave (qsub, kh) owns keys
//      kh*32..+31 of each 64-key tile. Regs ~92/wave -> launch_bounds(256,5)
//      = 20 waves/CU (vs r12's 16); LDS 16.6KB. Per-SIMD pipes were all <20%
//      (CU-level counters /4) -> latency-bound, TLP is the lever; doubled
//      exp work is cheap. Plain-store epilogue.
//   4) flash_full : general path (scalar!=0). OWNER blocks (att 1,3): phase 0
//      computes inter, plain-stores; phase 1 computes intra, read-modify-
//      writes scv* by the SAME threads (no atomics, no zero-init). Exactly
//      complementary gating with flash_half in mixed-scalar cases.
//      S^T trick: A=K,B=Q so each lane holds its query's keys; P -> MFMA-A via
//      v_permlane32_swap_b32 in COPY form (r4-validated; in-place failed r5).
//      Fixed-max softmax in log2 domain; scalar den + shfl broadcast.

typedef __bf16 v8bf __attribute__((ext_vector_type(8)));
typedef float  v16f __attribute__((ext_vector_type(16)));
typedef unsigned int u32;

typedef __attribute__((address_space(1))) const void gvoid;
typedef __attribute__((address_space(3))) void svoid;

#define QSCALE 0.25500526817276613f  // log2(e)/sqrt(32)

union frag_u { u32 d[4]; v8bf v; };
union pk_u { unsigned short s[2]; u32 d; };

static __device__ inline u32 pack_bf16(float x, float y) {
  pk_u u;
  __bf16 a = (__bf16)x, b = (__bf16)y;
  u.s[0] = *(unsigned short*)&a;
  u.s[1] = *(unsigned short*)&b;
  return u.d;
}

// ---------------------------------------------------------------- deinterleave
__global__ __launch_bounds__(256) void deint_kernel(const float* __restrict__ x,
                                                    __bf16* __restrict__ xe,
                                                    __bf16* __restrict__ xp) {
  const size_t i = (size_t)blockIdx.x * 256 + threadIdx.x;
  const float4* xin = (const float4*)(x + i * 16);
  float4 a = xin[0], b = xin[1], c = xin[2], d = xin[3];
  v8bf ev, pv;
  ev[0]=(__bf16)a.x; ev[1]=(__bf16)a.z; ev[2]=(__bf16)b.x; ev[3]=(__bf16)b.z;
  ev[4]=(__bf16)c.x; ev[5]=(__bf16)c.z; ev[6]=(__bf16)d.x; ev[7]=(__bf16)d.z;
  pv[0]=(__bf16)a.y; pv[1]=(__bf16)a.w; pv[2]=(__bf16)b.y; pv[3]=(__bf16)b.w;
  pv[4]=(__bf16)c.y; pv[5]=(__bf16)c.w; pv[6]=(__bf16)d.y; pv[7]=(__bf16)d.w;
  *(v8bf*)(xe + i * 8) = ev;
  *(v8bf*)(xp + i * 8) = pv;
}

// ---------------------------------------------------------------- projections
struct ProjArgs {
  const __bf16* xe;
  const __bf16* xp;
  const float* w[12];
  __bf16* q[4];
  __bf16* k[4];
  __bf16* vt[4];
  const float* alpha;
  const float* gamma;
};

// grid (20 jobs, 128 row-tiles of 128), block 256 (4 waves, 32 rows, 64 cols).
__global__ __launch_bounds__(256) void proj_kernel(ProjArgs pa) {
  const int job = blockIdx.x;
  const int rb  = blockIdx.y * 128;
  const int tid = threadIdx.x;
  const int lane = tid & 63, w = tid >> 6;
  const int l31 = lane & 31, lh = lane >> 5;
  const int l7 = lane & 7, l8 = lane >> 3;

  // alpha/gamma-gated V jobs: V0 (w3, jobs 4-7, vi=0) needs alpha!=0;
  // V2 (w9, jobs 16-19, vi=3) needs gamma!=0. 0*finite == 0 exactly.
  if (job >= 4) {
    const int vi = (job - 4) >> 2;
    if (vi == 0 && pa.alpha[0] == 0.0f) return;
    if (vi == 3 && pa.gamma[0] == 0.0f) return;
  }

  __shared__ __bf16 lds_b[64][264];      // 64 n x 256 k (+8 pad, 528B rows)
  __shared__ __bf16 lds_a[2][128 * 64];  // dbuf BK=64, swizzled 128B rows

  int src, dout, wc0[2], vcol0 = 0, vmode = 0;
  const float* wp[2];
  __bf16* dqk[2] = {nullptr, nullptr};
  __bf16* vdst = nullptr;
  float sc = 1.0f;
  if (job < 4) {
    dout = 32; wc0[0] = 0; wc0[1] = 0;
    switch (job) {
      case 0: src=0; wp[0]=pa.w[0]; wp[1]=pa.w[3];  dqk[0]=pa.q[0]; dqk[1]=pa.q[1]; sc=QSCALE; break;
      case 1: src=0; wp[0]=pa.w[1]; wp[1]=pa.w[10]; dqk[0]=pa.k[0]; dqk[1]=pa.k[3]; break;
      case 2: src=1; wp[0]=pa.w[6]; wp[1]=pa.w[9];  dqk[0]=pa.q[2]; dqk[1]=pa.q[3]; sc=QSCALE; break;
      default:src=1; wp[0]=pa.w[4]; wp[1]=pa.w[7];  dqk[0]=pa.k[1]; dqk[1]=pa.k[2]; break;
    }
  } else {
    const int vi = (job - 4) >> 2, t = (job - 4) & 3;
    const int widx = (vi==0) ? 2 : (vi==1) ? 11 : (vi==2) ? 5 : 8;   // w3,w12,w6,w9
    const int vbuf = (vi==0) ? 0 : (vi==1) ? 3  : (vi==2) ? 1 : 2;   // V0,V3,V1,V2
    dout = 256; vmode = 1; src = vi >> 1;                            // e,e,p,p
    wp[0] = pa.w[widx]; wp[1] = pa.w[widx];
    wc0[0] = t*64; wc0[1] = t*64 + 32;
    vcol0 = t*64; vdst = pa.vt[vbuf];
  }

  // stage B transposed (once): lds_b[n][k] = w[k][c0+n]
  for (int h = 0; h < 2; ++h) {
    const float* wgt = wp[h]; const int c0 = wc0[h];
    for (int i = tid; i < 32*256; i += 256) {
      int n = i & 31, kk = i >> 5;
      lds_b[h*32 + n][kk] = (__bf16)wgt[(size_t)kk*dout + c0 + n];
    }
  }

  const __bf16* X = src ? pa.xp : pa.xe;
  const char* agbase = (const char*)(X + (size_t)rb*256) + (size_t)(l7 ^ l8)*16
                     + (size_t)l8*512;

  // stage A slice kb into buf (rows (w*4+i)*8 + l8, swizzled chunk l7^l8)
#define STAGE_A(buf, kb)                                                        \
  {                                                                             \
    const char* g = agbase + (size_t)(kb)*128;                                  \
    _Pragma("unroll")                                                           \
    for (int i = 0; i < 4; ++i)                                                 \
      __builtin_amdgcn_global_load_lds(                                         \
          (gvoid*)(g + (size_t)(w*4 + i)*8*512),                                \
          (svoid*)&lds_a[buf][((w*4 + i)*8)*64 + lane*8], 16, 0, 0);            \
  }

  STAGE_A(0, 0)
  __syncthreads();

  v16f acc[2];
#pragma unroll
  for (int n = 0; n < 2; ++n)
#pragma unroll
    for (int i = 0; i < 16; ++i) acc[n][i] = 0.f;

  for (int kb = 0; kb < 4; ++kb) {
    if (kb < 3) STAGE_A((kb + 1) & 1, kb + 1)
    const __bf16* ab = &lds_a[kb & 1][0];
#pragma unroll
    for (int kk = 0; kk < 4; ++kk) {
      const v8bf af = *(const v8bf*)&ab[(w*32 + l31)*64 + (((kk*2 + lh) ^ (l31 & 7))*8)];
#pragma unroll
      for (int nt = 0; nt < 2; ++nt) {
        const v8bf bf = *(const v8bf*)&lds_b[nt*32 + l31][kb*64 + kk*16 + lh*8];
        acc[nt] = __builtin_amdgcn_mfma_f32_32x32x16_bf16(af, bf, acc[nt], 0, 0, 0);
      }
    }
    __syncthreads();
  }

  if (!vmode) {
    // Q/K row-major [16384][32]
#pragma unroll
    for (int nt = 0; nt < 2; ++nt) {
      __bf16* dst = dqk[nt];
#pragma unroll
      for (int r = 0; r < 16; ++r) {
        const int row = rb + w*32 + (r & 3) + 8*(r >> 2) + 4*lh;
        dst[(size_t)row*32 + l31] = (__bf16)(acc[nt][r] * sc);
      }
    }
  } else {
    // V: transpose through LDS (reuse lds_a), then write GLOBAL FRAGMENT-SLOT
    // layout: Vf[(bb*32+kt64)*2048 + (nt*8 + kc2)*32 + v5] 16B slots.
    __bf16 (*lds_t)[136] = (__bf16 (*)[136])&lds_a[0][0];  // 64 x 136 (272B rows)
#pragma unroll
    for (int nt = 0; nt < 2; ++nt) {
#pragma unroll
      for (int r = 0; r < 16; ++r) {
        const int row = w*32 + (r & 3) + 8*(r >> 2) + 4*lh;
        lds_t[nt*32 + l31][row] = (__bf16)acc[nt][r];
      }
    }
    __syncthreads();
    const int bb = rb >> 11, ll0 = rb & 2047;
    const int nt0 = vcol0 >> 5;                       // t*2
    const size_t tbase = (size_t)(bb*32 + (ll0 >> 6));
    for (int i = tid; i < 1024; i += 256) {
      const int ktl = i >> 9, s = i & 511;
      const int h = s >> 8, kc2 = (s >> 5) & 7, v5 = s & 31;
      const int vrow = h*32 + v5, krow = ktl*64 + kc2*8;
      *(int4*)&vdst[((tbase + ktl)*2048 + (size_t)((nt0 + h)*8 + kc2)*32 + v5) * 8] =
          *(const int4*)&lds_t[vrow][krow];
    }
  }
}

// ---------------------------------------------------------------- flash attention
struct FlashArgs {
  const __bf16* q[4];
  const __bf16* k[4];
  const __bf16* v[4];
  const float* alpha;
  const float* gamma;
  float* out;
};

// ---------- FAST PATH: key-split + vh-split (scalar==0) -----------------------
// 2048 blocks x 256 thr. flat = qt*64 + vh*32 + pair (pair%8 pins XCD).
// Block = 64 q x 64 vcols (nt0f = nt0 + vh*2) x all 2048 keys. Wave (qsub, kh):
// 32 q rows, keys kh*32..+31 of each 64-key tile, NTN=2 vcol tiles.
// ~92 regs/wave (60 VGPR + 32 AGPR acc) -> 5 waves/SIMD, 20 waves/CU.
__global__ __launch_bounds__(256, 5) void flash_half(FlashArgs fa) {
  const int flat = blockIdx.x;
  const int pair = flat & 31;
  const int vh = (flat >> 5) & 1;
  const int qt = flat >> 6;            // 0..31
  const int att = pair & 3, bb = pair >> 2;
  const int tid = threadIdx.x;
  const int lane = tid & 63, w = tid >> 6;
  const int qsub = w >> 1, kh = w & 1;
  const int l31 = lane & 31, lh = lane >> 5;

  const float av = fa.alpha[0], gv = fa.gamma[0];
  int att_e, nt0;
  if (att == 0)      { if (av != 0.0f) return; att_e = 1; nt0 = 4; }
  else if (att == 1) { if (av != 0.0f) return; att_e = 1; nt0 = 0; }
  else if (att == 2) { if (gv != 0.0f) return; att_e = 3; nt0 = 4; }
  else               { if (gv != 0.0f) return; att_e = 3; nt0 = 0; }
  const int nt0f = nt0 + vh*2;

  __shared__ __bf16 v_lds[2][4096];  // 2 x 512 slots x 16B = 16KB
  __shared__ float dlds[2][32];      // cross-kh den handoff

  const __bf16* Qp = fa.q[att_e] + (size_t)(bb*2048 + qt*64 + qsub*32 + l31)*32;
  const __bf16* Kb = fa.k[att_e] + (size_t)bb*2048*32;
  const char* vgbase = (const char*)(fa.v[att_e] + (size_t)bb*32*16384)
                     + (size_t)(nt0f*256 + w*128 + lane)*16;
  float* outp = fa.out + (size_t)(bb*2048 + qt*64 + qsub*32)*512
              + (att_e >> 1)*256 + nt0f*32;

  // Q B-frags (resident): B[n=q=l31][k=d = c*16 + lh*8 + j]
  const v8bf qf0 = *(const v8bf*)&Qp[lh*8];
  const v8bf qf1 = *(const v8bf*)&Qp[16 + lh*8];

#define HSTAGE(buf_, kt_)                                                       \
  {                                                                             \
    const char* g = vgbase + (size_t)(kt_)*32768;                               \
    _Pragma("unroll")                                                           \
    for (int i = 0; i < 2; ++i)                                                 \
      __builtin_amdgcn_global_load_lds(                                         \
          (gvoid*)(g + (size_t)i*1024),                                         \
          (svoid*)&v_lds[buf_][(w*128 + 64*i)*8 + lane*8], 16, 0, 0);           \
  }

  // K A-frags for this wave's 32-key window of tile kt_: keys kt*64 + kh*32 + l31
#define HLOADK(a_, b_, kt_)                                                     \
  {                                                                             \
    const size_t kr = (size_t)((kt_)*64 + kh*32 + l31) * 32;                    \
    a_ = *(const v8bf*)&Kb[kr + lh*8];                                          \
    b_ = *(const v8bf*)&Kb[kr + 16 + lh*8];                                     \
  }

  v16f acc[2];
#pragma unroll
  for (int n = 0; n < 2; ++n)
#pragma unroll
    for (int i = 0; i < 16; ++i) acc[n][i] = 0.f;
  float den_s = 0.f;

  v8bf kfc0, kfc1;
  HLOADK(kfc0, kfc1, 0)
  HSTAGE(0, 0)
  __syncthreads();  // V(0) staged

#pragma unroll 1
  for (int kt = 0; kt < 32; ++kt) {
    const int cur = kt & 1;
    v8bf kfn0, kfn1;
    if (kt < 31) {
      HLOADK(kfn0, kfn1, kt + 1)      // latency hidden by compute
      HSTAGE(cur ^ 1, kt + 1)         // lands by end-of-kt barrier
    }

    // S^T = K.Q^T (log2 domain): C[row=key (this wave's 32)][col=q]
    v16f st;
#pragma unroll
    for (int i = 0; i < 16; ++i) st[i] = 0.f;
    st = __builtin_amdgcn_mfma_f32_32x32x16_bf16(kfc0, qf0, st, 0, 0, 0);
    st = __builtin_amdgcn_mfma_f32_32x32x16_bf16(kfc1, qf1, st, 0, 0, 0);

    // P = exp2(S^T): 16 values/lane
    u32 pk[8];
#pragma unroll
    for (int i = 0; i < 8; ++i) {
      const float e0 = __builtin_exp2f(st[2*i]);
      const float e1 = __builtin_exp2f(st[2*i + 1]);
      den_s += e0 + e1;
      pk[i] = pack_bf16(e0, e1);
    }

    // P C->A layout via v_permlane32_swap_b32, COPY form (r4-validated)
    v8bf pf[2];
#pragma unroll
    for (int f2 = 0; f2 < 2; ++f2) {
      u32 a0 = pk[f2*4 + 0], b0 = pk[f2*4 + 2];
      u32 a1 = pk[f2*4 + 1], b1 = pk[f2*4 + 3];
      asm("v_permlane32_swap_b32 %0, %1" : "+v"(a0), "+v"(b0));
      asm("v_permlane32_swap_b32 %0, %1" : "+v"(a1), "+v"(b1));
      frag_u fu;
      fu.d[0] = a0; fu.d[1] = a1; fu.d[2] = b0; fu.d[3] = b1;
      pf[f2] = fu.v;
    }

    // PV: this wave's 2 kc blocks (kc = kh*2 + j) x 2 nt
    const __bf16* vb = &v_lds[cur][0];
#pragma unroll
    for (int j = 0; j < 2; ++j) {
      const int kc = kh*2 + j;
#pragma unroll
      for (int nt = 0; nt < 2; ++nt) {
        const v8bf vf = *(const v8bf*)&vb[(nt*256 + kc*64 + lane)*8];
        acc[nt] = __builtin_amdgcn_mfma_f32_32x32x16_bf16(pf[j], vf, acc[nt], 0, 0, 0);
      }
    }

    __syncthreads();  // all waves done with cur buffer; V(kt+1) staged
    if (kt < 31) { kfc0 = kfn0; kfc1 = kfn1; }
  }

  // epilogue: combine the two kh-halves (acc element-wise, den per q), store.
  const float den_half = den_s + __shfl_xor(den_s, 32, 64);  // this wave's 32 keys
  float* alds = (float*)&v_lds[0][0];   // 4096 floats = 2 qsub x 2 nt x 16 r x 64
  if (kh) {
    if (lane < 32) dlds[qsub][l31] = den_half;
#pragma unroll
    for (int nt = 0; nt < 2; ++nt)
#pragma unroll
      for (int r = 0; r < 16; ++r)
        alds[qsub*2048 + nt*1024 + r*64 + lane] = acc[nt][r];
  }
  __syncthreads();
  if (!kh) {
    const float den_full = den_half + dlds[qsub][l31];
#pragma unroll
    for (int r = 0; r < 16; ++r) {
      const int row = (r & 3) + 8*(r >> 2) + 4*lh;
      const float f = 1.0f / __shfl(den_full, row, 64);
#pragma unroll
      for (int nt = 0; nt < 2; ++nt)
        outp[(size_t)row*512 + nt*32 + l31] =
            (acc[nt][r] + alds[qsub*2048 + nt*1024 + r*64 + lane]) * f;
    }
  }

#undef HSTAGE
#undef HLOADK
}

// ---------- GENERAL PATH: r7-validated NTN=8 body; plain-store / RMW ----------
template<int NTN, bool ACCUM>
__device__ __forceinline__ void flash_body(
    const __bf16* __restrict__ Qp, const __bf16* __restrict__ Kb,
    const char* __restrict__ vgbase, float scv, float* __restrict__ outp,
    __bf16* __restrict__ lds0, int lane, int w, int l31, int lh) {

  __bf16* vb0 = lds0;
  __bf16* vb1 = lds0 + NTN*2048;   // NTN*256 slots per buffer

  const v8bf qf0 = *(const v8bf*)&Qp[lh*8];
  const v8bf qf1 = *(const v8bf*)&Qp[16 + lh*8];

#define STAGE_V(dst_, kt_)                                                      \
  {                                                                             \
    const char* g = vgbase + (size_t)(kt_)*32768;                               \
    _Pragma("unroll")                                                           \
    for (int i = 0; i < NTN; ++i)                                               \
      __builtin_amdgcn_global_load_lds(                                         \
          (gvoid*)(g + (size_t)i*1024),                                         \
          (svoid*)&dst_[(w*NTN*64 + 64*i)*8 + lane*8], 16, 0, 0);               \
  }

  v16f acc[NTN];
#pragma unroll
  for (int n = 0; n < NTN; ++n)
#pragma unroll
    for (int i = 0; i < 16; ++i) acc[n][i] = 0.f;

  float den_s = 0.f;
  v8bf pf[4];
  v8bf kf00, kf01, kf10, kf11;
  v16f st0, st1;
  u32 pk0[8], pk1[8];

#define LOADK(kt_)                                                              \
  {                                                                             \
    const int kb_ = (kt_) * 64;                                                 \
    kf00 = *(const v8bf*)&Kb[((size_t)(kb_ +      l31))*32 +      lh*8];        \
    kf01 = *(const v8bf*)&Kb[((size_t)(kb_ +      l31))*32 + 16 + lh*8];        \
    kf10 = *(const v8bf*)&Kb[((size_t)(kb_ + 32 + l31))*32 +      lh*8];        \
    kf11 = *(const v8bf*)&Kb[((size_t)(kb_ + 32 + l31))*32 + 16 + lh*8];        \
  }

#define SMFMA                                                                   \
  {                                                                             \
    _Pragma("unroll")                                                           \
    for (int i = 0; i < 16; ++i) { st0[i] = 0.f; st1[i] = 0.f; }                \
    st0 = __builtin_amdgcn_mfma_f32_32x32x16_bf16(kf00, qf0, st0, 0, 0, 0);     \
    st0 = __builtin_amdgcn_mfma_f32_32x32x16_bf16(kf01, qf1, st0, 0, 0, 0);     \
    st1 = __builtin_amdgcn_mfma_f32_32x32x16_bf16(kf10, qf0, st1, 0, 0, 0);     \
    st1 = __builtin_amdgcn_mfma_f32_32x32x16_bf16(kf11, qf1, st1, 0, 0, 0);     \
  }

#define EXPH(st_, pk_)                                                          \
  _Pragma("unroll")                                                             \
  for (int i = 0; i < 8; ++i) {                                                 \
    const float e0 = __builtin_exp2f(st_[2*i]);                                 \
    const float e1 = __builtin_exp2f(st_[2*i + 1]);                             \
    den_s += e0 + e1;                                                           \
    pk_[i] = pack_bf16(e0, e1);                                                 \
  }

#define XCHG(pk_, o_)                                                           \
  _Pragma("unroll")                                                             \
  for (int f2 = 0; f2 < 2; ++f2) {                                              \
    u32 a0 = pk_[f2*4 + 0], b0 = pk_[f2*4 + 2];                                 \
    u32 a1 = pk_[f2*4 + 1], b1 = pk_[f2*4 + 3];                                 \
    asm("v_permlane32_swap_b32 %0, %1" : "+v"(a0), "+v"(b0));                   \
    asm("v_permlane32_swap_b32 %0, %1" : "+v"(a1), "+v"(b1));                   \
    frag_u fu;                                                                  \
    fu.d[0] = a0; fu.d[1] = a1; fu.d[2] = b0; fu.d[3] = b1;                     \
    pf[(o_) + f2] = fu.v;                                                       \
  }

#define PVBLK(kc_, vb_)                                                         \
  _Pragma("unroll")                                                             \
  for (int nt = 0; nt < NTN; ++nt) {                                            \
    const v8bf vf = *(const v8bf*)&vb_[(nt*256 + (kc_)*64 + lane)*8];           \
    acc[nt] = __builtin_amdgcn_mfma_f32_32x32x16_bf16(pf[kc_], vf, acc[nt], 0, 0, 0); \
  }

  LOADK(0)
  STAGE_V(vb0, 0)
  SMFMA
  EXPH(st0, pk0)
  EXPH(st1, pk1)
  XCHG(pk0, 0)
  XCHG(pk1, 2)
  __syncthreads();  // V(0) staged

  for (int kt = 0; kt < 31; ++kt) {
    const int cur = kt & 1;
    LOADK(kt + 1)
    if (cur) { STAGE_V(vb0, kt + 1) } else { STAGE_V(vb1, kt + 1) }
    const __bf16* vb = cur ? vb1 : vb0;

    PVBLK(0, vb)
    SMFMA
    PVBLK(1, vb)
    EXPH(st0, pk0)
    PVBLK(2, vb)
    EXPH(st1, pk1)
    XCHG(pk0, 0)
    PVBLK(3, vb)
    XCHG(pk1, 2)

    __syncthreads();
  }

  {
    PVBLK(0, vb1)
    PVBLK(1, vb1)
    PVBLK(2, vb1)
    PVBLK(3, vb1)
  }

  const float den_full = den_s + __shfl_xor(den_s, 32, 64);
#pragma unroll
  for (int r = 0; r < 16; ++r) {
    const int row = (r & 3) + 8*(r >> 2) + 4*lh;
    const float f = scv / __shfl(den_full, row, 64);
#pragma unroll
    for (int nt = 0; nt < NTN; ++nt) {
      const size_t idx = (size_t)row*512 + nt*32 + l31;
      const float v = acc[nt][r] * f;
      outp[idx] = ACCUM ? (outp[idx] + v) : v;   // same thread wrote phase 0
    }
  }

#undef STAGE_V
#undef LOADK
#undef SMFMA
#undef EXPH
#undef XCHG
#undef PVBLK
}

// 512 blocks x 256 thr. OWNER blocks att in {1,3} (att 0,2 idle): phase 0
// computes inter(att) and plain-stores; phase 1 computes intra(att-1) and
// read-modify-writes scv* by the same threads. Runs only when scalar != 0
// (flash_half covers the zero case) -- correctness path, perf-irrelevant here.
__global__ __launch_bounds__(256, 2) void flash_full(FlashArgs fa) {
  const int flat = blockIdx.x;
  const int pair = flat & 31, qt = flat >> 5;
  const int att = pair & 3, bb = pair >> 2;
  if (!(att & 1)) return;   // owners are att 1 (cols 0-255), att 3 (cols 256-511)

  const float scv = (att == 1) ? fa.alpha[0] : fa.gamma[0];
  if (scv == 0.0f) return;  // fast path owns this case

  const int tid = threadIdx.x;
  const int lane = tid & 63, w = tid >> 6;
  const int l31 = lane & 31, lh = lane >> 5;

  __shared__ __bf16 v_lds[2][16384];  // 2 x 2048 slots x 16B

  float* outp = fa.out + (size_t)(bb*2048 + qt*128 + w*32)*512 + (att >> 1)*256;

  {  // phase 0: inter (att), plain store
    const __bf16* Qp = fa.q[att] + (size_t)(bb*2048 + qt*128 + w*32 + l31)*32;
    const __bf16* Kb = fa.k[att] + (size_t)bb*2048*32;
    const char* vgbase = (const char*)(fa.v[att] + (size_t)bb*32*16384)
                       + (size_t)(w*512 + lane)*16;
    flash_body<8, false>(Qp, Kb, vgbase, 1.0f, outp, &v_lds[0][0], lane, w, l31, lh);
  }
  __syncthreads();
  {  // phase 1: intra (att-1), accumulate scv * result
    const int ai = att - 1;
    const __bf16* Qp = fa.q[ai] + (size_t)(bb*2048 + qt*128 + w*32 + l31)*32;
    const __bf16* Kb = fa.k[ai] + (size_t)bb*2048*32;
    const char* vgbase = (const char*)(fa.v[ai] + (size_t)bb*32*16384)
                       + (size_t)(w*512 + lane)*16;
    flash_body<8, true>(Qp, Kb, vgbase, scv, outp, &v_lds[0][0], lane, w, l31, lh);
  }
}

// ---------------------------------------------------------------- launch
extern "C" void kernel_launch(void* const* d_in, const int* in_sizes, int n_in,
                              void* d_out, int out_size, void* d_ws, size_t ws_size,
                              hipStream_t stream) {
  (void)in_sizes; (void)n_in; (void)out_size; (void)ws_size;

  __bf16* wsp = (__bf16*)d_ws;
  const size_t XE = (size_t)16384 * 256;
  const size_t QK = (size_t)16384 * 32;
  const size_t VT = (size_t)8 * 32 * 16384;   // 8 bb x 32 kt64 x 2048 slots x 8

  __bf16* xe = wsp;
  __bf16* xp = wsp + XE;

  ProjArgs pa;
  pa.xe = xe; pa.xp = xp;
  const float* x = (const float*)d_in[0];
  for (int i = 0; i < 12; ++i) pa.w[i] = (const float*)d_in[1 + i];
  __bf16* base = wsp + 2*XE;
  for (int i = 0; i < 4; ++i) pa.q[i]  = base + (size_t)i * QK;
  for (int i = 0; i < 4; ++i) pa.k[i]  = base + (size_t)(4 + i) * QK;
  for (int i = 0; i < 4; ++i) pa.vt[i] = base + 8*QK + (size_t)i * VT;
  pa.alpha = (const float*)d_in[13];
  pa.gamma = (const float*)d_in[14];

  // no memset: flash_half (or flash_full's phase-0 store) writes every element
  hipLaunchKernelGGL(deint_kernel, dim3(2048), dim3(256), 0, stream, x, xe, xp);
  hipLaunchKernelGGL(proj_kernel, dim3(20, 128), dim3(256), 0, stream, pa);

  FlashArgs fl;
  for (int i = 0; i < 4; ++i) { fl.q[i] = pa.q[i]; fl.k[i] = pa.k[i]; fl.v[i] = pa.vt[i]; }
  fl.alpha = (const float*)d_in[13];
  fl.gamma = (const float*)d_in[14];
  fl.out = (float*)d_out;
  hipLaunchKernelGGL(flash_half, dim3(2048), dim3(256), 0, stream, fl);
  hipLaunchKernelGGL(flash_full, dim3(512), dim3(256), 0, stream, fl);
}

// Round 14
// 214.259 us; speedup vs baseline: 1.1387x; 1.1387x over previous
//
#include <hip/hip_runtime.h>

// B=8, L=2048, C=256, D=32. Four attentions (ecg/pcg intra/inter),
// out = concat(inter + scalar*intra) -> (8,2048,512) f32.
//
// Pipeline (NO memset: every output element is plain-stored exactly once):
//   1) deint_kernel : x f32 interleaved -> xe, xp bf16 [16384][256]
//   2) proj_kernel  : r9-validated 20-job version. xe/xp @ w -> bf16 Q[4]
//      (pre-scaled log2e/sqrt(32)), K[4], V in GLOBAL FRAGMENT-SLOT ORDER
//      Vf[bb][kt64][slot]: slot(nt,kc2,v5)=(nt*8+kc2)*32+v5, 16B slots,
//      tile = 32KB. Gated V jobs exit when scalar == 0.
//   3) flash_half : FAST PATH (scalar==0), r12-validated (79us). KEY-SPLIT
//      waves: 1024 blocks x 256 thr; block = 64q x 128vc; wave (qsub, kh)
//      owns keys kh*32..+31 of each 64-key tile (softmax VALU divided, not
//      duplicated -- r13's vh-split duplicated exp and regressed 79->113:
//      VALUBusy 60->79%, VALU is the near-saturated pipe). (256,4) -> 16
//      waves/CU. Epilogue: kh=1 parks acc+den in freed V-LDS, one barrier,
//      kh=0 combines and plain-stores (covers all 512 out cols).
//   4) flash_full : general path (scalar!=0). OWNER blocks (att 1,3): phase 0
//      computes inter, plain-stores; phase 1 computes intra, read-modify-
//      writes scv* by the SAME threads (no atomics, no zero-init).
//      S^T trick: A=K,B=Q so each lane holds its query's keys; P -> MFMA-A via
//      v_permlane32_swap_b32 in COPY form (r4-validated; in-place failed r5).
//      Fixed-max softmax in log2 domain; scalar den + shfl broadcast.

typedef __bf16 v8bf __attribute__((ext_vector_type(8)));
typedef float  v16f __attribute__((ext_vector_type(16)));
typedef unsigned int u32;

typedef __attribute__((address_space(1))) const void gvoid;
typedef __attribute__((address_space(3))) void svoid;

#define QSCALE 0.25500526817276613f  // log2(e)/sqrt(32)

union frag_u { u32 d[4]; v8bf v; };
union pk_u { unsigned short s[2]; u32 d; };

static __device__ inline u32 pack_bf16(float x, float y) {
  pk_u u;
  __bf16 a = (__bf16)x, b = (__bf16)y;
  u.s[0] = *(unsigned short*)&a;
  u.s[1] = *(unsigned short*)&b;
  return u.d;
}

// ---------------------------------------------------------------- deinterleave
__global__ __launch_bounds__(256) void deint_kernel(const float* __restrict__ x,
                                                    __bf16* __restrict__ xe,
                                                    __bf16* __restrict__ xp) {
  const size_t i = (size_t)blockIdx.x * 256 + threadIdx.x;
  const float4* xin = (const float4*)(x + i * 16);
  float4 a = xin[0], b = xin[1], c = xin[2], d = xin[3];
  v8bf ev, pv;
  ev[0]=(__bf16)a.x; ev[1]=(__bf16)a.z; ev[2]=(__bf16)b.x; ev[3]=(__bf16)b.z;
  ev[4]=(__bf16)c.x; ev[5]=(__bf16)c.z; ev[6]=(__bf16)d.x; ev[7]=(__bf16)d.z;
  pv[0]=(__bf16)a.y; pv[1]=(__bf16)a.w; pv[2]=(__bf16)b.y; pv[3]=(__bf16)b.w;
  pv[4]=(__bf16)c.y; pv[5]=(__bf16)c.w; pv[6]=(__bf16)d.y; pv[7]=(__bf16)d.w;
  *(v8bf*)(xe + i * 8) = ev;
  *(v8bf*)(xp + i * 8) = pv;
}

// ---------------------------------------------------------------- projections
struct ProjArgs {
  const __bf16* xe;
  const __bf16* xp;
  const float* w[12];
  __bf16* q[4];
  __bf16* k[4];
  __bf16* vt[4];
  const float* alpha;
  const float* gamma;
};

// grid (20 jobs, 128 row-tiles of 128), block 256 (4 waves, 32 rows, 64 cols).
__global__ __launch_bounds__(256) void proj_kernel(ProjArgs pa) {
  const int job = blockIdx.x;
  const int rb  = blockIdx.y * 128;
  const int tid = threadIdx.x;
  const int lane = tid & 63, w = tid >> 6;
  const int l31 = lane & 31, lh = lane >> 5;
  const int l7 = lane & 7, l8 = lane >> 3;

  // alpha/gamma-gated V jobs: V0 (w3, jobs 4-7, vi=0) needs alpha!=0;
  // V2 (w9, jobs 16-19, vi=3) needs gamma!=0. 0*finite == 0 exactly.
  if (job >= 4) {
    const int vi = (job - 4) >> 2;
    if (vi == 0 && pa.alpha[0] == 0.0f) return;
    if (vi == 3 && pa.gamma[0] == 0.0f) return;
  }

  __shared__ __bf16 lds_b[64][264];      // 64 n x 256 k (+8 pad, 528B rows)
  __shared__ __bf16 lds_a[2][128 * 64];  // dbuf BK=64, swizzled 128B rows

  int src, dout, wc0[2], vcol0 = 0, vmode = 0;
  const float* wp[2];
  __bf16* dqk[2] = {nullptr, nullptr};
  __bf16* vdst = nullptr;
  float sc = 1.0f;
  if (job < 4) {
    dout = 32; wc0[0] = 0; wc0[1] = 0;
    switch (job) {
      case 0: src=0; wp[0]=pa.w[0]; wp[1]=pa.w[3];  dqk[0]=pa.q[0]; dqk[1]=pa.q[1]; sc=QSCALE; break;
      case 1: src=0; wp[0]=pa.w[1]; wp[1]=pa.w[10]; dqk[0]=pa.k[0]; dqk[1]=pa.k[3]; break;
      case 2: src=1; wp[0]=pa.w[6]; wp[1]=pa.w[9];  dqk[0]=pa.q[2]; dqk[1]=pa.q[3]; sc=QSCALE; break;
      default:src=1; wp[0]=pa.w[4]; wp[1]=pa.w[7];  dqk[0]=pa.k[1]; dqk[1]=pa.k[2]; break;
    }
  } else {
    const int vi = (job - 4) >> 2, t = (job - 4) & 3;
    const int widx = (vi==0) ? 2 : (vi==1) ? 11 : (vi==2) ? 5 : 8;   // w3,w12,w6,w9
    const int vbuf = (vi==0) ? 0 : (vi==1) ? 3  : (vi==2) ? 1 : 2;   // V0,V3,V1,V2
    dout = 256; vmode = 1; src = vi >> 1;                            // e,e,p,p
    wp[0] = pa.w[widx]; wp[1] = pa.w[widx];
    wc0[0] = t*64; wc0[1] = t*64 + 32;
    vcol0 = t*64; vdst = pa.vt[vbuf];
  }

  // stage B transposed (once): lds_b[n][k] = w[k][c0+n]
  for (int h = 0; h < 2; ++h) {
    const float* wgt = wp[h]; const int c0 = wc0[h];
    for (int i = tid; i < 32*256; i += 256) {
      int n = i & 31, kk = i >> 5;
      lds_b[h*32 + n][kk] = (__bf16)wgt[(size_t)kk*dout + c0 + n];
    }
  }

  const __bf16* X = src ? pa.xp : pa.xe;
  const char* agbase = (const char*)(X + (size_t)rb*256) + (size_t)(l7 ^ l8)*16
                     + (size_t)l8*512;

  // stage A slice kb into buf (rows (w*4+i)*8 + l8, swizzled chunk l7^l8)
#define STAGE_A(buf, kb)                                                        \
  {                                                                             \
    const char* g = agbase + (size_t)(kb)*128;                                  \
    _Pragma("unroll")                                                           \
    for (int i = 0; i < 4; ++i)                                                 \
      __builtin_amdgcn_global_load_lds(                                         \
          (gvoid*)(g + (size_t)(w*4 + i)*8*512),                                \
          (svoid*)&lds_a[buf][((w*4 + i)*8)*64 + lane*8], 16, 0, 0);            \
  }

  STAGE_A(0, 0)
  __syncthreads();

  v16f acc[2];
#pragma unroll
  for (int n = 0; n < 2; ++n)
#pragma unroll
    for (int i = 0; i < 16; ++i) acc[n][i] = 0.f;

  for (int kb = 0; kb < 4; ++kb) {
    if (kb < 3) STAGE_A((kb + 1) & 1, kb + 1)
    const __bf16* ab = &lds_a[kb & 1][0];
#pragma unroll
    for (int kk = 0; kk < 4; ++kk) {
      const v8bf af = *(const v8bf*)&ab[(w*32 + l31)*64 + (((kk*2 + lh) ^ (l31 & 7))*8)];
#pragma unroll
      for (int nt = 0; nt < 2; ++nt) {
        const v8bf bf = *(const v8bf*)&lds_b[nt*32 + l31][kb*64 + kk*16 + lh*8];
        acc[nt] = __builtin_amdgcn_mfma_f32_32x32x16_bf16(af, bf, acc[nt], 0, 0, 0);
      }
    }
    __syncthreads();
  }

  if (!vmode) {
    // Q/K row-major [16384][32]
#pragma unroll
    for (int nt = 0; nt < 2; ++nt) {
      __bf16* dst = dqk[nt];
#pragma unroll
      for (int r = 0; r < 16; ++r) {
        const int row = rb + w*32 + (r & 3) + 8*(r >> 2) + 4*lh;
        dst[(size_t)row*32 + l31] = (__bf16)(acc[nt][r] * sc);
      }
    }
  } else {
    // V: transpose through LDS (reuse lds_a), then write GLOBAL FRAGMENT-SLOT
    // layout: Vf[(bb*32+kt64)*2048 + (nt*8 + kc2)*32 + v5] 16B slots.
    __bf16 (*lds_t)[136] = (__bf16 (*)[136])&lds_a[0][0];  // 64 x 136 (272B rows)
#pragma unroll
    for (int nt = 0; nt < 2; ++nt) {
#pragma unroll
      for (int r = 0; r < 16; ++r) {
        const int row = w*32 + (r & 3) + 8*(r >> 2) + 4*lh;
        lds_t[nt*32 + l31][row] = (__bf16)acc[nt][r];
      }
    }
    __syncthreads();
    const int bb = rb >> 11, ll0 = rb & 2047;
    const int nt0 = vcol0 >> 5;                       // t*2
    const size_t tbase = (size_t)(bb*32 + (ll0 >> 6));
    for (int i = tid; i < 1024; i += 256) {
      const int ktl = i >> 9, s = i & 511;
      const int h = s >> 8, kc2 = (s >> 5) & 7, v5 = s & 31;
      const int vrow = h*32 + v5, krow = ktl*64 + kc2*8;
      *(int4*)&vdst[((tbase + ktl)*2048 + (size_t)((nt0 + h)*8 + kc2)*32 + v5) * 8] =
          *(const int4*)&lds_t[vrow][krow];
    }
  }
}

// ---------------------------------------------------------------- flash attention
struct FlashArgs {
  const __bf16* q[4];
  const __bf16* k[4];
  const __bf16* v[4];
  const float* alpha;
  const float* gamma;
  float* out;
};

// ---------- FAST PATH: key-split waves (scalar==0), r12-validated -------------
// 1024 blocks x 256 thr. flat: pair = flat&31 (att,bb -> XCD pin), qt = flat>>5.
// Block = 64 q x 128 vcols x all 2048 keys. Wave (qsub = w>>1, kh = w&1):
// 32 q rows, keys kh*32..+31 of each 64-key tile, NTN=4 vcol tiles.
// Softmax VALU divided across kh (16 exp/kt/wave), not duplicated.
__global__ __launch_bounds__(256, 4) void flash_half(FlashArgs fa) {
  const int flat = blockIdx.x;
  const int pair = flat & 31, qt = flat >> 5;
  const int att = pair & 3, bb = pair >> 2;
  const int tid = threadIdx.x;
  const int lane = tid & 63, w = tid >> 6;
  const int qsub = w >> 1, kh = w & 1;
  const int l31 = lane & 31, lh = lane >> 5;

  const float av = fa.alpha[0], gv = fa.gamma[0];
  int att_e, nt0;
  if (att == 0)      { if (av != 0.0f) return; att_e = 1; nt0 = 4; }
  else if (att == 1) { if (av != 0.0f) return; att_e = 1; nt0 = 0; }
  else if (att == 2) { if (gv != 0.0f) return; att_e = 3; nt0 = 4; }
  else               { if (gv != 0.0f) return; att_e = 3; nt0 = 0; }

  __shared__ __bf16 v_lds[2][8192];  // 2 x 1024 slots x 16B = 32KB
  __shared__ float dlds[2][32];      // cross-kh den handoff

  const __bf16* Qp = fa.q[att_e] + (size_t)(bb*2048 + qt*64 + qsub*32 + l31)*32;
  const __bf16* Kb = fa.k[att_e] + (size_t)bb*2048*32;
  const char* vgbase = (const char*)(fa.v[att_e] + (size_t)bb*32*16384)
                     + (size_t)(nt0*256 + w*256 + lane)*16;
  float* outp = fa.out + (size_t)(bb*2048 + qt*64 + qsub*32)*512
              + (att_e >> 1)*256 + nt0*32;

  // Q B-frags (resident): B[n=q=l31][k=d = c*16 + lh*8 + j]
  const v8bf qf0 = *(const v8bf*)&Qp[lh*8];
  const v8bf qf1 = *(const v8bf*)&Qp[16 + lh*8];

#define HSTAGE(buf_, kt_)                                                       \
  {                                                                             \
    const char* g = vgbase + (size_t)(kt_)*32768;                               \
    _Pragma("unroll")                                                           \
    for (int i = 0; i < 4; ++i)                                                 \
      __builtin_amdgcn_global_load_lds(                                         \
          (gvoid*)(g + (size_t)i*1024),                                         \
          (svoid*)&v_lds[buf_][(w*256 + 64*i)*8 + lane*8], 16, 0, 0);           \
  }

  // K A-frags for this wave's 32-key window of tile kt_: keys kt*64 + kh*32 + l31
#define HLOADK(a_, b_, kt_)                                                     \
  {                                                                             \
    const size_t kr = (size_t)((kt_)*64 + kh*32 + l31) * 32;                    \
    a_ = *(const v8bf*)&Kb[kr + lh*8];                                          \
    b_ = *(const v8bf*)&Kb[kr + 16 + lh*8];                                     \
  }

  v16f acc[4];
#pragma unroll
  for (int n = 0; n < 4; ++n)
#pragma unroll
    for (int i = 0; i < 16; ++i) acc[n][i] = 0.f;
  float den_s = 0.f;

  v8bf kfc0, kfc1;
  HLOADK(kfc0, kfc1, 0)
  HSTAGE(0, 0)
  __syncthreads();  // V(0) staged

#pragma unroll 1
  for (int kt = 0; kt < 32; ++kt) {
    const int cur = kt & 1;
    v8bf kfn0, kfn1;
    if (kt < 31) {
      HLOADK(kfn0, kfn1, kt + 1)      // latency hidden by compute
      HSTAGE(cur ^ 1, kt + 1)         // lands by end-of-kt barrier
    }

    // S^T = K.Q^T (log2 domain): C[row=key (this wave's 32)][col=q]
    v16f st;
#pragma unroll
    for (int i = 0; i < 16; ++i) st[i] = 0.f;
    st = __builtin_amdgcn_mfma_f32_32x32x16_bf16(kfc0, qf0, st, 0, 0, 0);
    st = __builtin_amdgcn_mfma_f32_32x32x16_bf16(kfc1, qf1, st, 0, 0, 0);

    // P = exp2(S^T): 16 values/lane (half of r9's 32)
    u32 pk[8];
#pragma unroll
    for (int i = 0; i < 8; ++i) {
      const float e0 = __builtin_exp2f(st[2*i]);
      const float e1 = __builtin_exp2f(st[2*i + 1]);
      den_s += e0 + e1;
      pk[i] = pack_bf16(e0, e1);
    }

    // P C->A layout via v_permlane32_swap_b32, COPY form (r4-validated)
    v8bf pf[2];
#pragma unroll
    for (int f2 = 0; f2 < 2; ++f2) {
      u32 a0 = pk[f2*4 + 0], b0 = pk[f2*4 + 2];
      u32 a1 = pk[f2*4 + 1], b1 = pk[f2*4 + 3];
      asm("v_permlane32_swap_b32 %0, %1" : "+v"(a0), "+v"(b0));
      asm("v_permlane32_swap_b32 %0, %1" : "+v"(a1), "+v"(b1));
      frag_u fu;
      fu.d[0] = a0; fu.d[1] = a1; fu.d[2] = b0; fu.d[3] = b1;
      pf[f2] = fu.v;
    }

    // PV: this wave's 2 kc blocks (kc = kh*2 + j) x 4 nt
    const __bf16* vb = &v_lds[cur][0];
#pragma unroll
    for (int j = 0; j < 2; ++j) {
      const int kc = kh*2 + j;
#pragma unroll
      for (int nt = 0; nt < 4; ++nt) {
        const v8bf vf = *(const v8bf*)&vb[(nt*256 + kc*64 + lane)*8];
        acc[nt] = __builtin_amdgcn_mfma_f32_32x32x16_bf16(pf[j], vf, acc[nt], 0, 0, 0);
      }
    }

    __syncthreads();  // all waves done with cur buffer; V(kt+1) staged
    if (kt < 31) { kfc0 = kfn0; kfc1 = kfn1; }
  }

  // epilogue: combine the two kh-halves (acc element-wise, den per q), store.
  const float den_half = den_s + __shfl_xor(den_s, 32, 64);  // this wave's 32 keys
  float* alds = (float*)&v_lds[0][0];   // 8192 floats = 2 qsub x 4 nt x 16 r x 64
  if (kh) {
    if (lane < 32) dlds[qsub][l31] = den_half;
#pragma unroll
    for (int nt = 0; nt < 4; ++nt)
#pragma unroll
      for (int r = 0; r < 16; ++r)
        alds[qsub*4096 + nt*1024 + r*64 + lane] = acc[nt][r];
  }
  __syncthreads();
  if (!kh) {
    const float den_full = den_half + dlds[qsub][l31];
#pragma unroll
    for (int r = 0; r < 16; ++r) {
      const int row = (r & 3) + 8*(r >> 2) + 4*lh;
      const float f = 1.0f / __shfl(den_full, row, 64);
#pragma unroll
      for (int nt = 0; nt < 4; ++nt)
        outp[(size_t)row*512 + nt*32 + l31] =
            (acc[nt][r] + alds[qsub*4096 + nt*1024 + r*64 + lane]) * f;
    }
  }

#undef HSTAGE
#undef HLOADK
}

// ---------- GENERAL PATH: r7-validated NTN=8 body; plain-store / RMW ----------
template<int NTN, bool ACCUM>
__device__ __forceinline__ void flash_body(
    const __bf16* __restrict__ Qp, const __bf16* __restrict__ Kb,
    const char* __restrict__ vgbase, float scv, float* __restrict__ outp,
    __bf16* __restrict__ lds0, int lane, int w, int l31, int lh) {

  __bf16* vb0 = lds0;
  __bf16* vb1 = lds0 + NTN*2048;   // NTN*256 slots per buffer

  const v8bf qf0 = *(const v8bf*)&Qp[lh*8];
  const v8bf qf1 = *(const v8bf*)&Qp[16 + lh*8];

#define STAGE_V(dst_, kt_)                                                      \
  {                                                                             \
    const char* g = vgbase + (size_t)(kt_)*32768;                               \
    _Pragma("unroll")                                                           \
    for (int i = 0; i < NTN; ++i)                                               \
      __builtin_amdgcn_global_load_lds(                                         \
          (gvoid*)(g + (size_t)i*1024),                                         \
          (svoid*)&dst_[(w*NTN*64 + 64*i)*8 + lane*8], 16, 0, 0);               \
  }

  v16f acc[NTN];
#pragma unroll
  for (int n = 0; n < NTN; ++n)
#pragma unroll
    for (int i = 0; i < 16; ++i) acc[n][i] = 0.f;

  float den_s = 0.f;
  v8bf pf[4];
  v8bf kf00, kf01, kf10, kf11;
  v16f st0, st1;
  u32 pk0[8], pk1[8];

#define LOADK(kt_)                                                              \
  {                                                                             \
    const int kb_ = (kt_) * 64;                                                 \
    kf00 = *(const v8bf*)&Kb[((size_t)(kb_ +      l31))*32 +      lh*8];        \
    kf01 = *(const v8bf*)&Kb[((size_t)(kb_ +      l31))*32 + 16 + lh*8];        \
    kf10 = *(const v8bf*)&Kb[((size_t)(kb_ + 32 + l31))*32 +      lh*8];        \
    kf11 = *(const v8bf*)&Kb[((size_t)(kb_ + 32 + l31))*32 + 16 + lh*8];        \
  }

#define SMFMA                                                                   \
  {                                                                             \
    _Pragma("unroll")                                                           \
    for (int i = 0; i < 16; ++i) { st0[i] = 0.f; st1[i] = 0.f; }                \
    st0 = __builtin_amdgcn_mfma_f32_32x32x16_bf16(kf00, qf0, st0, 0, 0, 0);     \
    st0 = __builtin_amdgcn_mfma_f32_32x32x16_bf16(kf01, qf1, st0, 0, 0, 0);     \
    st1 = __builtin_amdgcn_mfma_f32_32x32x16_bf16(kf10, qf0, st1, 0, 0, 0);     \
    st1 = __builtin_amdgcn_mfma_f32_32x32x16_bf16(kf11, qf1, st1, 0, 0, 0);     \
  }

#define EXPH(st_, pk_)                                                          \
  _Pragma("unroll")                                                             \
  for (int i = 0; i < 8; ++i) {                                                 \
    const float e0 = __builtin_exp2f(st_[2*i]);                                 \
    const float e1 = __builtin_exp2f(st_[2*i + 1]);                             \
    den_s += e0 + e1;                                                           \
    pk_[i] = pack_bf16(e0, e1);                                                 \
  }

#define XCHG(pk_, o_)                                                           \
  _Pragma("unroll")                                                             \
  for (int f2 = 0; f2 < 2; ++f2) {                                              \
    u32 a0 = pk_[f2*4 + 0], b0 = pk_[f2*4 + 2];                                 \
    u32 a1 = pk_[f2*4 + 1], b1 = pk_[f2*4 + 3];                                 \
    asm("v_permlane32_swap_b32 %0, %1" : "+v"(a0), "+v"(b0));                   \
    asm("v_permlane32_swap_b32 %0, %1" : "+v"(a1), "+v"(b1));                   \
    frag_u fu;                                                                  \
    fu.d[0] = a0; fu.d[1] = a1; fu.d[2] = b0; fu.d[3] = b1;                     \
    pf[(o_) + f2] = fu.v;                                                       \
  }

#define PVBLK(kc_, vb_)                                                         \
  _Pragma("unroll")                                                             \
  for (int nt = 0; nt < NTN; ++nt) {                                            \
    const v8bf vf = *(const v8bf*)&vb_[(nt*256 + (kc_)*64 + lane)*8];           \
    acc[nt] = __builtin_amdgcn_mfma_f32_32x32x16_bf16(pf[kc_], vf, acc[nt], 0, 0, 0); \
  }

  LOADK(0)
  STAGE_V(vb0, 0)
  SMFMA
  EXPH(st0, pk0)
  EXPH(st1, pk1)
  XCHG(pk0, 0)
  XCHG(pk1, 2)
  __syncthreads();  // V(0) staged

  for (int kt = 0; kt < 31; ++kt) {
    const int cur = kt & 1;
    LOADK(kt + 1)
    if (cur) { STAGE_V(vb0, kt + 1) } else { STAGE_V(vb1, kt + 1) }
    const __bf16* vb = cur ? vb1 : vb0;

    PVBLK(0, vb)
    SMFMA
    PVBLK(1, vb)
    EXPH(st0, pk0)
    PVBLK(2, vb)
    EXPH(st1, pk1)
    XCHG(pk0, 0)
    PVBLK(3, vb)
    XCHG(pk1, 2)

    __syncthreads();
  }

  {
    PVBLK(0, vb1)
    PVBLK(1, vb1)
    PVBLK(2, vb1)
    PVBLK(3, vb1)
  }

  const float den_full = den_s + __shfl_xor(den_s, 32, 64);
#pragma unroll
  for (int r = 0; r < 16; ++r) {
    const int row = (r & 3) + 8*(r >> 2) + 4*lh;
    const float f = scv / __shfl(den_full, row, 64);
#pragma unroll
    for (int nt = 0; nt < NTN; ++nt) {
      const size_t idx = (size_t)row*512 + nt*32 + l31;
      const float v = acc[nt][r] * f;
      outp[idx] = ACCUM ? (outp[idx] + v) : v;   // same thread wrote phase 0
    }
  }

#undef STAGE_V
#undef LOADK
#undef SMFMA
#undef EXPH
#undef XCHG
#undef PVBLK
}

// 512 blocks x 256 thr. OWNER blocks att in {1,3} (att 0,2 idle): phase 0
// computes inter(att) and plain-stores; phase 1 computes intra(att-1) and
// read-modify-writes scv* by the same threads. Runs only when scalar != 0
// (flash_half covers the zero case) -- correctness path, perf-irrelevant here.
__global__ __launch_bounds__(256, 2) void flash_full(FlashArgs fa) {
  const int flat = blockIdx.x;
  const int pair = flat & 31, qt = flat >> 5;
  const int att = pair & 3, bb = pair >> 2;
  if (!(att & 1)) return;   // owners are att 1 (cols 0-255), att 3 (cols 256-511)

  const float scv = (att == 1) ? fa.alpha[0] : fa.gamma[0];
  if (scv == 0.0f) return;  // fast path owns this case

  const int tid = threadIdx.x;
  const int lane = tid & 63, w = tid >> 6;
  const int l31 = lane & 31, lh = lane >> 5;

  __shared__ __bf16 v_lds[2][16384];  // 2 x 2048 slots x 16B

  float* outp = fa.out + (size_t)(bb*2048 + qt*128 + w*32)*512 + (att >> 1)*256;

  {  // phase 0: inter (att), plain store
    const __bf16* Qp = fa.q[att] + (size_t)(bb*2048 + qt*128 + w*32 + l31)*32;
    const __bf16* Kb = fa.k[att] + (size_t)bb*2048*32;
    const char* vgbase = (const char*)(fa.v[att] + (size_t)bb*32*16384)
                       + (size_t)(w*512 + lane)*16;
    flash_body<8, false>(Qp, Kb, vgbase, 1.0f, outp, &v_lds[0][0], lane, w, l31, lh);
  }
  __syncthreads();
  {  // phase 1: intra (att-1), accumulate scv * result
    const int ai = att - 1;
    const __bf16* Qp = fa.q[ai] + (size_t)(bb*2048 + qt*128 + w*32 + l31)*32;
    const __bf16* Kb = fa.k[ai] + (size_t)bb*2048*32;
    const char* vgbase = (const char*)(fa.v[ai] + (size_t)bb*32*16384)
                       + (size_t)(w*512 + lane)*16;
    flash_body<8, true>(Qp, Kb, vgbase, scv, outp, &v_lds[0][0], lane, w, l31, lh);
  }
}

// ---------------------------------------------------------------- launch
extern "C" void kernel_launch(void* const* d_in, const int* in_sizes, int n_in,
                              void* d_out, int out_size, void* d_ws, size_t ws_size,
                              hipStream_t stream) {
  (void)in_sizes; (void)n_in; (void)out_size; (void)ws_size;

  __bf16* wsp = (__bf16*)d_ws;
  const size_t XE = (size_t)16384 * 256;
  const size_t QK = (size_t)16384 * 32;
  const size_t VT = (size_t)8 * 32 * 16384;   // 8 bb x 32 kt64 x 2048 slots x 8

  __bf16* xe = wsp;
  __bf16* xp = wsp + XE;

  ProjArgs pa;
  pa.xe = xe; pa.xp = xp;
  const float* x = (const float*)d_in[0];
  for (int i = 0; i < 12; ++i) pa.w[i] = (const float*)d_in[1 + i];
  __bf16* base = wsp + 2*XE;
  for (int i = 0; i < 4; ++i) pa.q[i]  = base + (size_t)i * QK;
  for (int i = 0; i < 4; ++i) pa.k[i]  = base + (size_t)(4 + i) * QK;
  for (int i = 0; i < 4; ++i) pa.vt[i] = base + 8*QK + (size_t)i * VT;
  pa.alpha = (const float*)d_in[13];
  pa.gamma = (const float*)d_in[14];

  // no memset: flash_half (or flash_full's phase-0 store) writes every element
  hipLaunchKernelGGL(deint_kernel, dim3(2048), dim3(256), 0, stream, x, xe, xp);
  hipLaunchKernelGGL(proj_kernel, dim3(20, 128), dim3(256), 0, stream, pa);

  FlashArgs fl;
  for (int i = 0; i < 4; ++i) { fl.q[i] = pa.q[i]; fl.k[i] = pa.k[i]; fl.v[i] = pa.vt[i]; }
  fl.alpha = (const float*)d_in[13];
  fl.gamma = (const float*)d_in[14];
  fl.out = (float*)d_out;
  hipLaunchKernelGGL(flash_half, dim3(1024), dim3(256), 0, stream, fl);
  hipLaunchKernelGGL(flash_full, dim3(512), dim3(256), 0, stream, fl);
}

// Round 15
// 208.165 us; speedup vs baseline: 1.1720x; 1.0293x over previous
//
#include <hip/hip_runtime.h>

// B=8, L=2048, C=256, D=32. Four attentions (ecg/pcg intra/inter),
// out = concat(inter + scalar*intra) -> (8,2048,512) f32.
//
// Pipeline (NO memset: every output element is plain-stored exactly once):
//   1) deint_kernel : x f32 interleaved -> xe, xp bf16 [16384][256]
//   2) proj_kernel  : 20-job structure (r9), A-PATH REWORKED: A-frags load
//      DIRECTLY from global (per-lane 16B, row-major -- same pattern as
//      flash's K loads). lds_a deleted: A had ZERO cross-wave reuse (wave w
//      only ever read rows w*32..+31), so staging it cost 32KB LDS + 2
//      barriers/kb for nothing. LDS 66.5 -> 33.8KB => 4 blocks/CU (was 2);
//      ONE barrier total (after shared B stage). V-transpose scratch aliases
//      lds_b (dead after last MFMA; barrier before reuse).
//      Outputs: bf16 Q[4] (pre-scaled log2e/sqrt(32)), K[4], V in GLOBAL
//      FRAGMENT-SLOT ORDER Vf[bb][kt64][slot]: slot(nt,kc2,v5)=(nt*8+kc2)*32+v5,
//      16B slots, tile = 32KB. Gated V jobs exit when scalar == 0.
//   3) flash_half : FAST PATH (scalar==0), r12-validated (78us). KEY-SPLIT
//      waves: 1024 blocks x 256 thr; block = 64q x 128vc; wave (qsub, kh)
//      owns keys kh*32..+31 of each 64-key tile (softmax VALU divided, not
//      duplicated -- r13's vh-split duplicated exp and regressed). (256,4).
//      Epilogue: kh=1 parks acc+den in freed V-LDS, one barrier, kh=0
//      combines and plain-stores.
//   4) flash_full : general path (scalar!=0). OWNER blocks (att 1,3): phase 0
//      computes inter, plain-stores; phase 1 computes intra, read-modify-
//      writes scv* by the SAME threads (no atomics, no zero-init).
//      S^T trick: A=K,B=Q so each lane holds its query's keys; P -> MFMA-A via
//      v_permlane32_swap_b32 in COPY form (r4-validated; in-place failed r5).
//      Fixed-max softmax in log2 domain; scalar den + shfl broadcast.

typedef __bf16 v8bf __attribute__((ext_vector_type(8)));
typedef float  v16f __attribute__((ext_vector_type(16)));
typedef unsigned int u32;

typedef __attribute__((address_space(1))) const void gvoid;
typedef __attribute__((address_space(3))) void svoid;

#define QSCALE 0.25500526817276613f  // log2(e)/sqrt(32)

union frag_u { u32 d[4]; v8bf v; };
union pk_u { unsigned short s[2]; u32 d; };

static __device__ inline u32 pack_bf16(float x, float y) {
  pk_u u;
  __bf16 a = (__bf16)x, b = (__bf16)y;
  u.s[0] = *(unsigned short*)&a;
  u.s[1] = *(unsigned short*)&b;
  return u.d;
}

// ---------------------------------------------------------------- deinterleave
__global__ __launch_bounds__(256) void deint_kernel(const float* __restrict__ x,
                                                    __bf16* __restrict__ xe,
                                                    __bf16* __restrict__ xp) {
  const size_t i = (size_t)blockIdx.x * 256 + threadIdx.x;
  const float4* xin = (const float4*)(x + i * 16);
  float4 a = xin[0], b = xin[1], c = xin[2], d = xin[3];
  v8bf ev, pv;
  ev[0]=(__bf16)a.x; ev[1]=(__bf16)a.z; ev[2]=(__bf16)b.x; ev[3]=(__bf16)b.z;
  ev[4]=(__bf16)c.x; ev[5]=(__bf16)c.z; ev[6]=(__bf16)d.x; ev[7]=(__bf16)d.z;
  pv[0]=(__bf16)a.y; pv[1]=(__bf16)a.w; pv[2]=(__bf16)b.y; pv[3]=(__bf16)b.w;
  pv[4]=(__bf16)c.y; pv[5]=(__bf16)c.w; pv[6]=(__bf16)d.y; pv[7]=(__bf16)d.w;
  *(v8bf*)(xe + i * 8) = ev;
  *(v8bf*)(xp + i * 8) = pv;
}

// ---------------------------------------------------------------- projections
struct ProjArgs {
  const __bf16* xe;
  const __bf16* xp;
  const float* w[12];
  __bf16* q[4];
  __bf16* k[4];
  __bf16* vt[4];
  const float* alpha;
  const float* gamma;
};

// grid (20 jobs, 128 row-tiles of 128), block 256 (4 waves, 32 rows, 64 cols).
// A-frags direct from global; only B (shared by all waves) staged in LDS.
__global__ __launch_bounds__(256) void proj_kernel(ProjArgs pa) {
  const int job = blockIdx.x;
  const int rb  = blockIdx.y * 128;
  const int tid = threadIdx.x;
  const int lane = tid & 63, w = tid >> 6;
  const int l31 = lane & 31, lh = lane >> 5;

  // alpha/gamma-gated V jobs: V0 (w3, jobs 4-7, vi=0) needs alpha!=0;
  // V2 (w9, jobs 16-19, vi=3) needs gamma!=0. 0*finite == 0 exactly.
  if (job >= 4) {
    const int vi = (job - 4) >> 2;
    if (vi == 0 && pa.alpha[0] == 0.0f) return;
    if (vi == 3 && pa.gamma[0] == 0.0f) return;
  }

  __shared__ __bf16 lds_b[64][264];  // 33.8KB; aliased as 64x136 V-transpose buf

  int src, dout, wc0[2], vcol0 = 0, vmode = 0;
  const float* wp[2];
  __bf16* dqk[2] = {nullptr, nullptr};
  __bf16* vdst = nullptr;
  float sc = 1.0f;
  if (job < 4) {
    dout = 32; wc0[0] = 0; wc0[1] = 0;
    switch (job) {
      case 0: src=0; wp[0]=pa.w[0]; wp[1]=pa.w[3];  dqk[0]=pa.q[0]; dqk[1]=pa.q[1]; sc=QSCALE; break;
      case 1: src=0; wp[0]=pa.w[1]; wp[1]=pa.w[10]; dqk[0]=pa.k[0]; dqk[1]=pa.k[3]; break;
      case 2: src=1; wp[0]=pa.w[6]; wp[1]=pa.w[9];  dqk[0]=pa.q[2]; dqk[1]=pa.q[3]; sc=QSCALE; break;
      default:src=1; wp[0]=pa.w[4]; wp[1]=pa.w[7];  dqk[0]=pa.k[1]; dqk[1]=pa.k[2]; break;
    }
  } else {
    const int vi = (job - 4) >> 2, t = (job - 4) & 3;
    const int widx = (vi==0) ? 2 : (vi==1) ? 11 : (vi==2) ? 5 : 8;   // w3,w12,w6,w9
    const int vbuf = (vi==0) ? 0 : (vi==1) ? 3  : (vi==2) ? 1 : 2;   // V0,V3,V1,V2
    dout = 256; vmode = 1; src = vi >> 1;                            // e,e,p,p
    wp[0] = pa.w[widx]; wp[1] = pa.w[widx];
    wc0[0] = t*64; wc0[1] = t*64 + 32;
    vcol0 = t*64; vdst = pa.vt[vbuf];
  }

  // stage B transposed (once): lds_b[n][k] = w[k][c0+n]
  for (int h = 0; h < 2; ++h) {
    const float* wgt = wp[h]; const int c0 = wc0[h];
    for (int i = tid; i < 32*256; i += 256) {
      int n = i & 31, kk = i >> 5;
      lds_b[h*32 + n][kk] = (__bf16)wgt[(size_t)kk*dout + c0 + n];
    }
  }
  __syncthreads();  // the ONLY pre-epilogue barrier

  // A row for this lane (row-major X): A[m = w*32 + l31][k]
  const __bf16* X = src ? pa.xp : pa.xe;
  const __bf16* arow = X + (size_t)(rb + w*32 + l31) * 256;

  v16f acc[2];
#pragma unroll
  for (int n = 0; n < 2; ++n)
#pragma unroll
    for (int i = 0; i < 16; ++i) acc[n][i] = 0.f;

#pragma unroll
  for (int kb = 0; kb < 4; ++kb) {
#pragma unroll
    for (int kk = 0; kk < 4; ++kk) {
      const v8bf af = *(const v8bf*)&arow[kb*64 + kk*16 + lh*8];
#pragma unroll
      for (int nt = 0; nt < 2; ++nt) {
        const v8bf bf = *(const v8bf*)&lds_b[nt*32 + l31][kb*64 + kk*16 + lh*8];
        acc[nt] = __builtin_amdgcn_mfma_f32_32x32x16_bf16(af, bf, acc[nt], 0, 0, 0);
      }
    }
  }

  if (!vmode) {
    // Q/K row-major [16384][32] -- no barrier needed (acc in registers)
#pragma unroll
    for (int nt = 0; nt < 2; ++nt) {
      __bf16* dst = dqk[nt];
#pragma unroll
      for (int r = 0; r < 16; ++r) {
        const int row = rb + w*32 + (r & 3) + 8*(r >> 2) + 4*lh;
        dst[(size_t)row*32 + l31] = (__bf16)(acc[nt][r] * sc);
      }
    }
  } else {
    // V: transpose via lds_b-alias (B dead after last MFMA), then write GLOBAL
    // FRAGMENT-SLOT layout: Vf[(bb*32+kt64)*2048 + (nt*8 + kc2)*32 + v5].
    __syncthreads();  // all waves done reading lds_b
    __bf16 (*lds_t)[136] = (__bf16 (*)[136])&lds_b[0][0];  // 64 x 136 (17.4KB)
#pragma unroll
    for (int nt = 0; nt < 2; ++nt) {
#pragma unroll
      for (int r = 0; r < 16; ++r) {
        const int row = w*32 + (r & 3) + 8*(r >> 2) + 4*lh;
        lds_t[nt*32 + l31][row] = (__bf16)acc[nt][r];
      }
    }
    __syncthreads();
    const int bb = rb >> 11, ll0 = rb & 2047;
    const int nt0 = vcol0 >> 5;                       // t*2
    const size_t tbase = (size_t)(bb*32 + (ll0 >> 6));
    for (int i = tid; i < 1024; i += 256) {
      const int ktl = i >> 9, s = i & 511;
      const int h = s >> 8, kc2 = (s >> 5) & 7, v5 = s & 31;
      const int vrow = h*32 + v5, krow = ktl*64 + kc2*8;
      *(int4*)&vdst[((tbase + ktl)*2048 + (size_t)((nt0 + h)*8 + kc2)*32 + v5) * 8] =
          *(const int4*)&lds_t[vrow][krow];
    }
  }
}

// ---------------------------------------------------------------- flash attention
struct FlashArgs {
  const __bf16* q[4];
  const __bf16* k[4];
  const __bf16* v[4];
  const float* alpha;
  const float* gamma;
  float* out;
};

// ---------- FAST PATH: key-split waves (scalar==0), r12-validated -------------
// 1024 blocks x 256 thr. flat: pair = flat&31 (att,bb -> XCD pin), qt = flat>>5.
// Block = 64 q x 128 vcols x all 2048 keys. Wave (qsub = w>>1, kh = w&1):
// 32 q rows, keys kh*32..+31 of each 64-key tile, NTN=4 vcol tiles.
// Softmax VALU divided across kh (16 exp/kt/wave), not duplicated.
__global__ __launch_bounds__(256, 4) void flash_half(FlashArgs fa) {
  const int flat = blockIdx.x;
  const int pair = flat & 31, qt = flat >> 5;
  const int att = pair & 3, bb = pair >> 2;
  const int tid = threadIdx.x;
  const int lane = tid & 63, w = tid >> 6;
  const int qsub = w >> 1, kh = w & 1;
  const int l31 = lane & 31, lh = lane >> 5;

  const float av = fa.alpha[0], gv = fa.gamma[0];
  int att_e, nt0;
  if (att == 0)      { if (av != 0.0f) return; att_e = 1; nt0 = 4; }
  else if (att == 1) { if (av != 0.0f) return; att_e = 1; nt0 = 0; }
  else if (att == 2) { if (gv != 0.0f) return; att_e = 3; nt0 = 4; }
  else               { if (gv != 0.0f) return; att_e = 3; nt0 = 0; }

  __shared__ __bf16 v_lds[2][8192];  // 2 x 1024 slots x 16B = 32KB
  __shared__ float dlds[2][32];      // cross-kh den handoff

  const __bf16* Qp = fa.q[att_e] + (size_t)(bb*2048 + qt*64 + qsub*32 + l31)*32;
  const __bf16* Kb = fa.k[att_e] + (size_t)bb*2048*32;
  const char* vgbase = (const char*)(fa.v[att_e] + (size_t)bb*32*16384)
                     + (size_t)(nt0*256 + w*256 + lane)*16;
  float* outp = fa.out + (size_t)(bb*2048 + qt*64 + qsub*32)*512
              + (att_e >> 1)*256 + nt0*32;

  // Q B-frags (resident): B[n=q=l31][k=d = c*16 + lh*8 + j]
  const v8bf qf0 = *(const v8bf*)&Qp[lh*8];
  const v8bf qf1 = *(const v8bf*)&Qp[16 + lh*8];

#define HSTAGE(buf_, kt_)                                                       \
  {                                                                             \
    const char* g = vgbase + (size_t)(kt_)*32768;                               \
    _Pragma("unroll")                                                           \
    for (int i = 0; i < 4; ++i)                                                 \
      __builtin_amdgcn_global_load_lds(                                         \
          (gvoid*)(g + (size_t)i*1024),                                         \
          (svoid*)&v_lds[buf_][(w*256 + 64*i)*8 + lane*8], 16, 0, 0);           \
  }

  // K A-frags for this wave's 32-key window of tile kt_: keys kt*64 + kh*32 + l31
#define HLOADK(a_, b_, kt_)                                                     \
  {                                                                             \
    const size_t kr = (size_t)((kt_)*64 + kh*32 + l31) * 32;                    \
    a_ = *(const v8bf*)&Kb[kr + lh*8];                                          \
    b_ = *(const v8bf*)&Kb[kr + 16 + lh*8];                                     \
  }

  v16f acc[4];
#pragma unroll
  for (int n = 0; n < 4; ++n)
#pragma unroll
    for (int i = 0; i < 16; ++i) acc[n][i] = 0.f;
  float den_s = 0.f;

  v8bf kfc0, kfc1;
  HLOADK(kfc0, kfc1, 0)
  HSTAGE(0, 0)
  __syncthreads();  // V(0) staged

#pragma unroll 1
  for (int kt = 0; kt < 32; ++kt) {
    const int cur = kt & 1;
    v8bf kfn0, kfn1;
    if (kt < 31) {
      HLOADK(kfn0, kfn1, kt + 1)      // latency hidden by compute
      HSTAGE(cur ^ 1, kt + 1)         // lands by end-of-kt barrier
    }

    // S^T = K.Q^T (log2 domain): C[row=key (this wave's 32)][col=q]
    v16f st;
#pragma unroll
    for (int i = 0; i < 16; ++i) st[i] = 0.f;
    st = __builtin_amdgcn_mfma_f32_32x32x16_bf16(kfc0, qf0, st, 0, 0, 0);
    st = __builtin_amdgcn_mfma_f32_32x32x16_bf16(kfc1, qf1, st, 0, 0, 0);

    // P = exp2(S^T): 16 values/lane (half of r9's 32)
    u32 pk[8];
#pragma unroll
    for (int i = 0; i < 8; ++i) {
      const float e0 = __builtin_exp2f(st[2*i]);
      const float e1 = __builtin_exp2f(st[2*i + 1]);
      den_s += e0 + e1;
      pk[i] = pack_bf16(e0, e1);
    }

    // P C->A layout via v_permlane32_swap_b32, COPY form (r4-validated)
    v8bf pf[2];
#pragma unroll
    for (int f2 = 0; f2 < 2; ++f2) {
      u32 a0 = pk[f2*4 + 0], b0 = pk[f2*4 + 2];
      u32 a1 = pk[f2*4 + 1], b1 = pk[f2*4 + 3];
      asm("v_permlane32_swap_b32 %0, %1" : "+v"(a0), "+v"(b0));
      asm("v_permlane32_swap_b32 %0, %1" : "+v"(a1), "+v"(b1));
      frag_u fu;
      fu.d[0] = a0; fu.d[1] = a1; fu.d[2] = b0; fu.d[3] = b1;
      pf[f2] = fu.v;
    }

    // PV: this wave's 2 kc blocks (kc = kh*2 + j) x 4 nt
    const __bf16* vb = &v_lds[cur][0];
#pragma unroll
    for (int j = 0; j < 2; ++j) {
      const int kc = kh*2 + j;
#pragma unroll
      for (int nt = 0; nt < 4; ++nt) {
        const v8bf vf = *(const v8bf*)&vb[(nt*256 + kc*64 + lane)*8];
        acc[nt] = __builtin_amdgcn_mfma_f32_32x32x16_bf16(pf[j], vf, acc[nt], 0, 0, 0);
      }
    }

    __syncthreads();  // all waves done with cur buffer; V(kt+1) staged
    if (kt < 31) { kfc0 = kfn0; kfc1 = kfn1; }
  }

  // epilogue: combine the two kh-halves (acc element-wise, den per q), store.
  const float den_half = den_s + __shfl_xor(den_s, 32, 64);  // this wave's 32 keys
  float* alds = (float*)&v_lds[0][0];   // 8192 floats = 2 qsub x 4 nt x 16 r x 64
  if (kh) {
    if (lane < 32) dlds[qsub][l31] = den_half;
#pragma unroll
    for (int nt = 0; nt < 4; ++nt)
#pragma unroll
      for (int r = 0; r < 16; ++r)
        alds[qsub*4096 + nt*1024 + r*64 + lane] = acc[nt][r];
  }
  __syncthreads();
  if (!kh) {
    const float den_full = den_half + dlds[qsub][l31];
#pragma unroll
    for (int r = 0; r < 16; ++r) {
      const int row = (r & 3) + 8*(r >> 2) + 4*lh;
      const float f = 1.0f / __shfl(den_full, row, 64);
#pragma unroll
      for (int nt = 0; nt < 4; ++nt)
        outp[(size_t)row*512 + nt*32 + l31] =
            (acc[nt][r] + alds[qsub*4096 + nt*1024 + r*64 + lane]) * f;
    }
  }

#undef HSTAGE
#undef HLOADK
}

// ---------- GENERAL PATH: r7-validated NTN=8 body; plain-store / RMW ----------
template<int NTN, bool ACCUM>
__device__ __forceinline__ void flash_body(
    const __bf16* __restrict__ Qp, const __bf16* __restrict__ Kb,
    const char* __restrict__ vgbase, float scv, float* __restrict__ outp,
    __bf16* __restrict__ lds0, int lane, int w, int l31, int lh) {

  __bf16* vb0 = lds0;
  __bf16* vb1 = lds0 + NTN*2048;   // NTN*256 slots per buffer

  const v8bf qf0 = *(const v8bf*)&Qp[lh*8];
  const v8bf qf1 = *(const v8bf*)&Qp[16 + lh*8];

#define STAGE_V(dst_, kt_)                                                      \
  {                                                                             \
    const char* g = vgbase + (size_t)(kt_)*32768;                               \
    _Pragma("unroll")                                                           \
    for (int i = 0; i < NTN; ++i)                                               \
      __builtin_amdgcn_global_load_lds(                                         \
          (gvoid*)(g + (size_t)i*1024),                                         \
          (svoid*)&dst_[(w*NTN*64 + 64*i)*8 + lane*8], 16, 0, 0);               \
  }

  v16f acc[NTN];
#pragma unroll
  for (int n = 0; n < NTN; ++n)
#pragma unroll
    for (int i = 0; i < 16; ++i) acc[n][i] = 0.f;

  float den_s = 0.f;
  v8bf pf[4];
  v8bf kf00, kf01, kf10, kf11;
  v16f st0, st1;
  u32 pk0[8], pk1[8];

#define LOADK(kt_)                                                              \
  {                                                                             \
    const int kb_ = (kt_) * 64;                                                 \
    kf00 = *(const v8bf*)&Kb[((size_t)(kb_ +      l31))*32 +      lh*8];        \
    kf01 = *(const v8bf*)&Kb[((size_t)(kb_ +      l31))*32 + 16 + lh*8];        \
    kf10 = *(const v8bf*)&Kb[((size_t)(kb_ + 32 + l31))*32 +      lh*8];        \
    kf11 = *(const v8bf*)&Kb[((size_t)(kb_ + 32 + l31))*32 + 16 + lh*8];        \
  }

#define SMFMA                                                                   \
  {                                                                             \
    _Pragma("unroll")                                                           \
    for (int i = 0; i < 16; ++i) { st0[i] = 0.f; st1[i] = 0.f; }                \
    st0 = __builtin_amdgcn_mfma_f32_32x32x16_bf16(kf00, qf0, st0, 0, 0, 0);     \
    st0 = __builtin_amdgcn_mfma_f32_32x32x16_bf16(kf01, qf1, st0, 0, 0, 0);     \
    st1 = __builtin_amdgcn_mfma_f32_32x32x16_bf16(kf10, qf0, st1, 0, 0, 0);     \
    st1 = __builtin_amdgcn_mfma_f32_32x32x16_bf16(kf11, qf1, st1, 0, 0, 0);     \
  }

#define EXPH(st_, pk_)                                                          \
  _Pragma("unroll")                                                             \
  for (int i = 0; i < 8; ++i) {                                                 \
    const float e0 = __builtin_exp2f(st_[2*i]);                                 \
    const float e1 = __builtin_exp2f(st_[2*i + 1]);                             \
    den_s += e0 + e1;                                                           \
    pk_[i] = pack_bf16(e0, e1);                                                 \
  }

#define XCHG(pk_, o_)                                                           \
  _Pragma("unroll")                                                             \
  for (int f2 = 0; f2 < 2; ++f2) {                                              \
    u32 a0 = pk_[f2*4 + 0], b0 = pk_[f2*4 + 2];                                 \
    u32 a1 = pk_[f2*4 + 1], b1 = pk_[f2*4 + 3];                                 \
    asm("v_permlane32_swap_b32 %0, %1" : "+v"(a0), "+v"(b0));                   \
    asm("v_permlane32_swap_b32 %0, %1" : "+v"(a1), "+v"(b1));                   \
    frag_u fu;                                                                  \
    fu.d[0] = a0; fu.d[1] = a1; fu.d[2] = b0; fu.d[3] = b1;                     \
    pf[(o_) + f2] = fu.v;                                                       \
  }

#define PVBLK(kc_, vb_)                                                         \
  _Pragma("unroll")                                                             \
  for (int nt = 0; nt < NTN; ++nt) {                                            \
    const v8bf vf = *(const v8bf*)&vb_[(nt*256 + (kc_)*64 + lane)*8];           \
    acc[nt] = __builtin_amdgcn_mfma_f32_32x32x16_bf16(pf[kc_], vf, acc[nt], 0, 0, 0); \
  }

  LOADK(0)
  STAGE_V(vb0, 0)
  SMFMA
  EXPH(st0, pk0)
  EXPH(st1, pk1)
  XCHG(pk0, 0)
  XCHG(pk1, 2)
  __syncthreads();  // V(0) staged

  for (int kt = 0; kt < 31; ++kt) {
    const int cur = kt & 1;
    LOADK(kt + 1)
    if (cur) { STAGE_V(vb0, kt + 1) } else { STAGE_V(vb1, kt + 1) }
    const __bf16* vb = cur ? vb1 : vb0;

    PVBLK(0, vb)
    SMFMA
    PVBLK(1, vb)
    EXPH(st0, pk0)
    PVBLK(2, vb)
    EXPH(st1, pk1)
    XCHG(pk0, 0)
    PVBLK(3, vb)
    XCHG(pk1, 2)

    __syncthreads();
  }

  {
    PVBLK(0, vb1)
    PVBLK(1, vb1)
    PVBLK(2, vb1)
    PVBLK(3, vb1)
  }

  const float den_full = den_s + __shfl_xor(den_s, 32, 64);
#pragma unroll
  for (int r = 0; r < 16; ++r) {
    const int row = (r & 3) + 8*(r >> 2) + 4*lh;
    const float f = scv / __shfl(den_full, row, 64);
#pragma unroll
    for (int nt = 0; nt < NTN; ++nt) {
      const size_t idx = (size_t)row*512 + nt*32 + l31;
      const float v = acc[nt][r] * f;
      outp[idx] = ACCUM ? (outp[idx] + v) : v;   // same thread wrote phase 0
    }
  }

#undef STAGE_V
#undef LOADK
#undef SMFMA
#undef EXPH
#undef XCHG
#undef PVBLK
}

// 512 blocks x 256 thr. OWNER blocks att in {1,3} (att 0,2 idle): phase 0
// computes inter(att) and plain-stores; phase 1 computes intra(att-1) and
// read-modify-writes scv* by the same threads. Runs only when scalar != 0
// (flash_half covers the zero case) -- correctness path, perf-irrelevant here.
__global__ __launch_bounds__(256, 2) void flash_full(FlashArgs fa) {
  const int flat = blockIdx.x;
  const int pair = flat & 31, qt = flat >> 5;
  const int att = pair & 3, bb = pair >> 2;
  if (!(att & 1)) return;   // owners are att 1 (cols 0-255), att 3 (cols 256-511)

  const float scv = (att == 1) ? fa.alpha[0] : fa.gamma[0];
  if (scv == 0.0f) return;  // fast path owns this case

  const int tid = threadIdx.x;
  const int lane = tid & 63, w = tid >> 6;
  const int l31 = lane & 31, lh = lane >> 5;

  __shared__ __bf16 v_lds[2][16384];  // 2 x 2048 slots x 16B

  float* outp = fa.out + (size_t)(bb*2048 + qt*128 + w*32)*512 + (att >> 1)*256;

  {  // phase 0: inter (att), plain store
    const __bf16* Qp = fa.q[att] + (size_t)(bb*2048 + qt*128 + w*32 + l31)*32;
    const __bf16* Kb = fa.k[att] + (size_t)bb*2048*32;
    const char* vgbase = (const char*)(fa.v[att] + (size_t)bb*32*16384)
                       + (size_t)(w*512 + lane)*16;
    flash_body<8, false>(Qp, Kb, vgbase, 1.0f, outp, &v_lds[0][0], lane, w, l31, lh);
  }
  __syncthreads();
  {  // phase 1: intra (att-1), accumulate scv * result
    const int ai = att - 1;
    const __bf16* Qp = fa.q[ai] + (size_t)(bb*2048 + qt*128 + w*32 + l31)*32;
    const __bf16* Kb = fa.k[ai] + (size_t)bb*2048*32;
    const char* vgbase = (const char*)(fa.v[ai] + (size_t)bb*32*16384)
                       + (size_t)(w*512 + lane)*16;
    flash_body<8, true>(Qp, Kb, vgbase, scv, outp, &v_lds[0][0], lane, w, l31, lh);
  }
}

// ---------------------------------------------------------------- launch
extern "C" void kernel_launch(void* const* d_in, const int* in_sizes, int n_in,
                              void* d_out, int out_size, void* d_ws, size_t ws_size,
                              hipStream_t stream) {
  (void)in_sizes; (void)n_in; (void)out_size; (void)ws_size;

  __bf16* wsp = (__bf16*)d_ws;
  const size_t XE = (size_t)16384 * 256;
  const size_t QK = (size_t)16384 * 32;
  const size_t VT = (size_t)8 * 32 * 16384;   // 8 bb x 32 kt64 x 2048 slots x 8

  __bf16* xe = wsp;
  __bf16* xp = wsp + XE;

  ProjArgs pa;
  pa.xe = xe; pa.xp = xp;
  const float* x = (const float*)d_in[0];
  for (int i = 0; i < 12; ++i) pa.w[i] = (const float*)d_in[1 + i];
  __bf16* base = wsp + 2*XE;
  for (int i = 0; i < 4; ++i) pa.q[i]  = base + (size_t)i * QK;
  for (int i = 0; i < 4; ++i) pa.k[i]  = base + (size_t)(4 + i) * QK;
  for (int i = 0; i < 4; ++i) pa.vt[i] = base + 8*QK + (size_t)i * VT;
  pa.alpha = (const float*)d_in[13];
  pa.gamma = (const float*)d_in[14];

  // no memset: flash_half (or flash_full's phase-0 store) writes every element
  hipLaunchKernelGGL(deint_kernel, dim3(2048), dim3(256), 0, stream, x, xe, xp);
  hipLaunchKernelGGL(proj_kernel, dim3(20, 128), dim3(256), 0, stream, pa);

  FlashArgs fl;
  for (int i = 0; i < 4; ++i) { fl.q[i] = pa.q[i]; fl.k[i] = pa.k[i]; fl.v[i] = pa.vt[i]; }
  fl.alpha = (const float*)d_in[13];
  fl.gamma = (const float*)d_in[14];
  fl.out = (float*)d_out;
  hipLaunchKernelGGL(flash_half, dim3(1024), dim3(256), 0, stream, fl);
  hipLaunchKernelGGL(flash_full, dim3(512), dim3(256), 0, stream, fl);
}